// Round 3
// baseline (238.953 us; speedup 1.0000x reference)
//
#include <hip/hip_runtime.h>
#include <math.h>

#define DIM 512
#define CD 14
#define NCODES 16384
#define NTOK 8192
#define EPS 1e-5f
#define TPB 32  // tokens per block in k_entropy

// ws float layout:
//   [0 .. 16383]              avg_prob accumulators
//   [16384]                   per-sample entropy accumulator
//   [16385]                   commit accumulator
//   [16512 .. 16512+NTOK*CD)  h[t][c] — numpy-f32-emulated projection
#define WS_H 16512

__global__ __launch_bounds__(256) void k_zero(float* ws) {
    int i = blockIdx.x * 256 + threadIdx.x;
    if (i < NCODES + 16) ws[i] = 0.f;
}

// Bit-exact emulation of numpy f32 einsum('bnd,cd->bnc'):
// sum_of_products_contig_contig_outstride0_two with BASELINE SIMD
// (einsum is not runtime-dispatched; manylinux baseline = SSE2+SSE3):
//   npyv f32 = 4 lanes, npyv_muladd = separate mul + add (NO FMA),
//   per 16-elem iteration sub-blocks applied in order 3,2,1,0,
//   final npyv_sum via SSE3 hadd pairs: (l0+l1)+(l2+l3),
//   then + b_in[c] as one f32 add.
__global__ __launch_bounds__(256) void k_h(
    const float* __restrict__ x, const float* __restrict__ W_in,
    const float* __restrict__ b_in, float* __restrict__ ws)
{
#pragma clang fp contract(off)
    const int id = blockIdx.x * 256 + threadIdx.x;  // 448*256 == NTOK*CD exactly
    const int t = id / CD;
    const int c = id - t * CD;
    const float* xr = x + (size_t)t * DIM;
    const float* wr = W_in + (size_t)c * DIM;

    float a0 = 0.f, a1 = 0.f, a2 = 0.f, a3 = 0.f;

    #pragma unroll 2
    for (int i = 0; i < 32; ++i) {
        const float* xp = xr + i * 16;
        const float* wp = wr + i * 16;
        const float4 x3 = *(const float4*)(xp + 12);
        const float4 w3 = *(const float4*)(wp + 12);
        const float4 x2 = *(const float4*)(xp + 8);
        const float4 w2 = *(const float4*)(wp + 8);
        const float4 x1 = *(const float4*)(xp + 4);
        const float4 w1 = *(const float4*)(wp + 4);
        const float4 x0 = *(const float4*)(xp);
        const float4 w0 = *(const float4*)(wp);
        // ab3 = a3*b3 + vaccum
        a0 = (x3.x * w3.x) + a0;
        a1 = (x3.y * w3.y) + a1;
        a2 = (x3.z * w3.z) + a2;
        a3 = (x3.w * w3.w) + a3;
        // ab2 = a2*b2 + ab3
        a0 = (x2.x * w2.x) + a0;
        a1 = (x2.y * w2.y) + a1;
        a2 = (x2.z * w2.z) + a2;
        a3 = (x2.w * w2.w) + a3;
        // ab1 = a1*b1 + ab2
        a0 = (x1.x * w1.x) + a0;
        a1 = (x1.y * w1.y) + a1;
        a2 = (x1.z * w1.z) + a2;
        a3 = (x1.w * w1.w) + a3;
        // vaccum = a0*b0 + ab1
        a0 = (x0.x * w0.x) + a0;
        a1 = (x0.y * w0.y) + a1;
        a2 = (x0.z * w0.z) + a2;
        a3 = (x0.w * w0.w) + a3;
    }
    // npyv_sum_f32 (SSE3): hadd twice -> (l0+l1) + (l2+l3)
    const float s01 = a0 + a1;
    const float s23 = a2 + a3;
    const float sum = s01 + s23;
    ws[WS_H + id] = sum + b_in[c];
}

// One wave per token: signs from emulated h -> indices + out = s @ W_out^T + b_out.
__global__ __launch_bounds__(256) void k_project(
    const float* __restrict__ ws, const float* __restrict__ W_out,
    const float* __restrict__ b_out, float* __restrict__ out,
    float* __restrict__ idx_out)
{
    const int wave = threadIdx.x >> 6;
    const int lane = threadIdx.x & 63;
    const int tok  = blockIdx.x * 4 + wave;
    const float* hp = ws + WS_H + (size_t)tok * CD;

    float s[CD];
    int jstar = 0;
    #pragma unroll
    for (int c = 0; c < CD; ++c) {
        const bool pos = hp[c] > 0.f;
        s[c] = pos ? 1.f : -1.f;
        jstar |= (pos ? 1 : 0) << (13 - c);
    }
    if (lane == 0) idx_out[tok] = (float)jstar;

    #pragma unroll
    for (int r = 0; r < 8; ++r) {
        const int d = r * 64 + lane;
        float v = b_out[d];
        const float* wo = W_out + (size_t)d * CD;
        #pragma unroll
        for (int c = 0; c < CD; ++c) v = fmaf(s[c], wo[c], v);
        out[(size_t)tok * DIM + d] = v;
    }
}

// Factorized softmax over the 2^14 sign codebook.
// prob_j = (prod over mismatched bits of f_b) / Z,  f_b = exp(-400*|h|),  Z = prod(1+f_b).
__global__ __launch_bounds__(256) void k_entropy(
    const float* __restrict__ ws_h, float* __restrict__ ws)
{
    __shared__ float h_lds[TPB][CD];
    __shared__ float fb[16];
    __shared__ float tbl[256];
    __shared__ float red[256];

    const int tid = threadIdx.x;
    const int t0 = blockIdx.x * TPB;

    float commitAcc = 0.f;
    for (int idx = tid; idx < TPB * CD; idx += 256) {
        const float hv = ws_h[(size_t)t0 * CD + idx];
        h_lds[idx / CD][idx % CD] = hv;
        const float dd = fabsf(hv) - 1.f;   // (h - sign(h))^2 == (|h|-1)^2
        commitAcc = fmaf(dd, dd, commitAcc);
    }

    float entAcc = 0.f;
    float avga[64];
    #pragma unroll
    for (int k = 0; k < 64; ++k) avga[k] = 0.f;

    const int tl = tid & 127;
    const int th = tid >> 7;

    for (int t = 0; t < TPB; ++t) {
        __syncthreads();  // h_lds ready (t=0) / previous token's tbl reads done
        if (tid < CD) fb[13 - tid] = __expf(-400.f * fabsf(h_lds[t][tid]));
        __syncthreads();  // fb ready

        // tbl[0..127]: subset products over fb[0..6]; tbl[128..255]: over fb[7..13]
        float v = 1.f;
        #pragma unroll
        for (int b = 0; b < 7; ++b)
            if (tl & (1 << b)) v *= fb[b + 7 * th];
        tbl[tid] = v;

        int jstar = 0;
        #pragma unroll
        for (int c = 0; c < CD; ++c)
            if (h_lds[t][c] > 0.f) jstar |= 1 << (13 - c);
        float Z = 1.f;
        #pragma unroll
        for (int b = 0; b < CD; ++b) Z *= 1.f + fb[b];
        const float invZ = 1.f / Z;
        __syncthreads();  // tbl ready

        const int xl = jstar & 127;
        const int xh = jstar >> 7;
        const float uLZ = tbl[tl ^ xl] * invZ;
        #pragma unroll 8
        for (int k = 0; k < 64; ++k) {
            const float p = uLZ * tbl[128 + ((th + 2 * k) ^ xh)];
            avga[k] += p;
            entAcc = fmaf(p, __logf(fmaxf(p, EPS)), entAcc);
        }
    }

    #pragma unroll 8
    for (int k = 0; k < 64; ++k)
        atomicAdd(&ws[tid + 256 * k], avga[k]);

    __syncthreads();
    red[tid] = entAcc;
    __syncthreads();
    for (int sft = 128; sft > 0; sft >>= 1) {
        if (tid < sft) red[tid] += red[tid + sft];
        __syncthreads();
    }
    if (tid == 0) atomicAdd(&ws[NCODES], red[0]);
    __syncthreads();
    red[tid] = commitAcc;
    __syncthreads();
    for (int sft = 128; sft > 0; sft >>= 1) {
        if (tid < sft) red[tid] += red[tid + sft];
        __syncthreads();
    }
    if (tid == 0) atomicAdd(&ws[NCODES + 1], red[0]);
}

__global__ __launch_bounds__(256) void k_final(
    const float* __restrict__ ws, float* __restrict__ aux_out)
{
    __shared__ float red[256];
    const int tid = threadIdx.x;
    float acc = 0.f;
    for (int k = tid; k < NCODES; k += 256) {
        const float ap = ws[k] * (1.f / 8192.f);
        acc = fmaf(ap, __logf(fmaxf(ap, EPS)), acc);
    }
    red[tid] = acc;
    __syncthreads();
    for (int s = 128; s > 0; s >>= 1) {
        if (tid < s) red[tid] += red[tid + s];
        __syncthreads();
    }
    if (tid == 0) {
        const float cbH = -red[0];
        const float psH = -ws[NCODES] * (1.f / 8192.f);
        const float commit = ws[NCODES + 1] * (1.f / (8192.f * 14.f));
        aux_out[0] = (psH - 1.0f * cbH) * 0.1f + commit * 0.25f;
    }
}

extern "C" void kernel_launch(void* const* d_in, const int* in_sizes, int n_in,
                              void* d_out, int out_size, void* d_ws, size_t ws_size,
                              hipStream_t stream) {
    const float* x     = (const float*)d_in[0];
    const float* W_in  = (const float*)d_in[1];
    const float* b_in  = (const float*)d_in[2];
    const float* W_out = (const float*)d_in[3];
    const float* b_out = (const float*)d_in[4];
    // d_in[5] (codebook) is implicit in the factorized math.

    float* out     = (float*)d_out;                 // [4*2048*512]
    float* idx_out = out + (size_t)NTOK * DIM;      // [8192] as float
    float* aux_out = idx_out + NTOK;                // [1]
    float* ws      = (float*)d_ws;

    hipLaunchKernelGGL(k_zero, dim3((NCODES + 16 + 255) / 256), dim3(256), 0, stream, ws);
    hipLaunchKernelGGL(k_h, dim3((NTOK * CD) / 256), dim3(256), 0, stream,
                       x, W_in, b_in, ws);
    hipLaunchKernelGGL(k_project, dim3(NTOK / 4), dim3(256), 0, stream,
                       ws, W_out, b_out, out, idx_out);
    hipLaunchKernelGGL(k_entropy, dim3(NTOK / TPB), dim3(256), 0, stream,
                       ws + WS_H, ws);
    hipLaunchKernelGGL(k_final, dim3(1), dim3(256), 0, stream, ws, aux_out);
}

// Round 4
// 109.038 us; speedup vs baseline: 2.1915x; 2.1915x over previous
//
#include <hip/hip_runtime.h>
#include <math.h>

#define DIM 512
#define CD 14
#define NCODES 16384
#define NTOK 8192
#define EPS 1e-5f
#define LOG_EPS -11.5129254650f  // log(1e-5)
#define PTHRESH 1e-12f           // below this, p is invisible to f32 accumulation

// ws float layout:
//   [0 .. 16383]              avg_prob accumulators
//   [16384]                   Σ_t Σ_enum p·(max(log p, LOG_EPS) − LOG_EPS)
//   [16385]                   commit accumulator
//   [16512 .. 16512+NTOK*CD)  h[t][c] — numpy-f32-emulated projection
#define WS_H 16512

__global__ __launch_bounds__(256) void k_zero(float* ws) {
    int i = blockIdx.x * 256 + threadIdx.x;
    if (i < NCODES + 16) ws[i] = 0.f;
}

// Bit-exact emulation of numpy f32 einsum('bnd,cd->bnc'):
// sum_of_products_contig_contig_outstride0_two with BASELINE SIMD
// (einsum is not runtime-dispatched; manylinux baseline = SSE2+SSE3):
//   npyv f32 = 4 lanes, npyv_muladd = separate mul + add (NO FMA),
//   per 16-elem iteration sub-blocks applied in order 3,2,1,0,
//   final npyv_sum via SSE3 hadd pairs: (l0+l1)+(l2+l3),
//   then + b_in[c] as one f32 add.
// VALIDATED round 3 — do not change the arithmetic.
__global__ __launch_bounds__(256) void k_h(
    const float* __restrict__ x, const float* __restrict__ W_in,
    const float* __restrict__ b_in, float* __restrict__ ws)
{
#pragma clang fp contract(off)
    const int id = blockIdx.x * 256 + threadIdx.x;  // 448*256 == NTOK*CD exactly
    const int t = id / CD;
    const int c = id - t * CD;
    const float* xr = x + (size_t)t * DIM;
    const float* wr = W_in + (size_t)c * DIM;

    float a0 = 0.f, a1 = 0.f, a2 = 0.f, a3 = 0.f;

    #pragma unroll 2
    for (int i = 0; i < 32; ++i) {
        const float* xp = xr + i * 16;
        const float* wp = wr + i * 16;
        const float4 x3 = *(const float4*)(xp + 12);
        const float4 w3 = *(const float4*)(wp + 12);
        const float4 x2 = *(const float4*)(xp + 8);
        const float4 w2 = *(const float4*)(wp + 8);
        const float4 x1 = *(const float4*)(xp + 4);
        const float4 w1 = *(const float4*)(wp + 4);
        const float4 x0 = *(const float4*)(xp);
        const float4 w0 = *(const float4*)(wp);
        a0 = (x3.x * w3.x) + a0;
        a1 = (x3.y * w3.y) + a1;
        a2 = (x3.z * w3.z) + a2;
        a3 = (x3.w * w3.w) + a3;
        a0 = (x2.x * w2.x) + a0;
        a1 = (x2.y * w2.y) + a1;
        a2 = (x2.z * w2.z) + a2;
        a3 = (x2.w * w2.w) + a3;
        a0 = (x1.x * w1.x) + a0;
        a1 = (x1.y * w1.y) + a1;
        a2 = (x1.z * w1.z) + a2;
        a3 = (x1.w * w1.w) + a3;
        a0 = (x0.x * w0.x) + a0;
        a1 = (x0.y * w0.y) + a1;
        a2 = (x0.z * w0.z) + a2;
        a3 = (x0.w * w0.w) + a3;
    }
    const float s01 = a0 + a1;
    const float s23 = a2 + a3;
    const float sum = s01 + s23;
    ws[WS_H + id] = sum + b_in[c];
}

// One wave per token: signs from emulated h -> indices + out = s @ W_out^T + b_out.
__global__ __launch_bounds__(256) void k_project(
    const float* __restrict__ ws, const float* __restrict__ W_out,
    const float* __restrict__ b_out, float* __restrict__ out,
    float* __restrict__ idx_out)
{
    const int wave = threadIdx.x >> 6;
    const int lane = threadIdx.x & 63;
    const int tok  = blockIdx.x * 4 + wave;
    const float* hp = ws + WS_H + (size_t)tok * CD;

    float s[CD];
    int jstar = 0;
    #pragma unroll
    for (int c = 0; c < CD; ++c) {
        const bool pos = hp[c] > 0.f;
        s[c] = pos ? 1.f : -1.f;
        jstar |= (pos ? 1 : 0) << (13 - c);
    }
    if (lane == 0) idx_out[tok] = (float)jstar;

    #pragma unroll
    for (int r = 0; r < 8; ++r) {
        const int d = r * 64 + lane;
        float v = b_out[d];
        const float* wo = W_out + (size_t)d * CD;
        #pragma unroll
        for (int c = 0; c < CD; ++c) v = fmaf(s[c], wo[c], v);
        out[(size_t)tok * DIM + d] = v;
    }
}

// Sparse clipped-softmax statistics. One thread per token.
// p_j = (prod over mismatched bits of f_b) / Z with f_b = exp(-400|h_b|).
// Only subsets of "hot" bits (f >= PTHRESH) can reach p >= PTHRESH; everything
// else is invisible to f32 accumulation. Exact identity used:
//   sum_j p_j * log(clip(p_j,eps)) = LOG_EPS + sum_{enum} p*(max(log p,LOG_EPS)-LOG_EPS)
__global__ __launch_bounds__(64) void k_sparse(
    const float* __restrict__ ws_h, float* __restrict__ ws)
{
    const int tok = blockIdx.x * 64 + threadIdx.x;  // 128 blocks * 64 == NTOK
    const float* hp = ws_h + (size_t)tok * CD;

    float f[CD];
    int jstar = 0;
    float commit = 0.f, Z = 1.f;
    #pragma unroll
    for (int c = 0; c < CD; ++c) {
        const float h = hp[c];
        if (h > 0.f) jstar |= 1 << (13 - c);
        const float a = fabsf(h);
        const float d = a - 1.f;
        commit = fmaf(d, d, commit);
        f[c] = __expf(-400.f * a);
        Z *= 1.f + f[c];
    }
    const float invZ = 1.f / Z;

    int   hbit[CD];
    float hf[CD];
    int m = 0;
    #pragma unroll
    for (int c = 0; c < CD; ++c) {
        if (f[c] >= PTHRESH) { hbit[m] = 1 << (13 - c); hf[m] = f[c]; ++m; }
    }

    float ent = 0.f;
    const int nmask = 1 << m;
    for (int mask = 0; mask < nmask; ++mask) {
        float prod = 1.f;
        int flip = 0;
        for (int i = 0; i < m; ++i)
            if ((mask >> i) & 1) { prod *= hf[i]; flip |= hbit[i]; }
        const float p = prod * invZ;
        if (p < PTHRESH) continue;
        const float lp = __logf(p);
        ent = fmaf(p, fmaxf(lp, LOG_EPS) - LOG_EPS, ent);
        atomicAdd(&ws[jstar ^ flip], p);
    }

    // wave reduction, one atomic per wave
    #pragma unroll
    for (int off = 32; off; off >>= 1) {
        ent    += __shfl_xor(ent, off);
        commit += __shfl_xor(commit, off);
    }
    if ((threadIdx.x & 63) == 0) {
        atomicAdd(&ws[NCODES], ent);
        atomicAdd(&ws[NCODES + 1], commit);
    }
}

__global__ __launch_bounds__(256) void k_final(
    const float* __restrict__ ws, float* __restrict__ aux_out)
{
    __shared__ float red[256];
    const int tid = threadIdx.x;
    float acc = 0.f;
    for (int k = tid; k < NCODES; k += 256) {
        const float ap = ws[k] * (1.f / 8192.f);
        acc = fmaf(ap, __logf(fmaxf(ap, EPS)), acc);
    }
    red[tid] = acc;
    __syncthreads();
    for (int s = 128; s > 0; s >>= 1) {
        if (tid < s) red[tid] += red[tid + s];
        __syncthreads();
    }
    if (tid == 0) {
        const float cbH = -red[0];
        // mean over tokens of sum_j p log(clip p)  ==  ws[NCODES]/NTOK + LOG_EPS
        const float psH = -(ws[NCODES] * (1.f / 8192.f) + LOG_EPS);
        const float commit = ws[NCODES + 1] * (1.f / (8192.f * 14.f));
        aux_out[0] = (psH - 1.0f * cbH) * 0.1f + commit * 0.25f;
    }
}

extern "C" void kernel_launch(void* const* d_in, const int* in_sizes, int n_in,
                              void* d_out, int out_size, void* d_ws, size_t ws_size,
                              hipStream_t stream) {
    const float* x     = (const float*)d_in[0];
    const float* W_in  = (const float*)d_in[1];
    const float* b_in  = (const float*)d_in[2];
    const float* W_out = (const float*)d_in[3];
    const float* b_out = (const float*)d_in[4];
    // d_in[5] (codebook) is implicit in the factorized math.

    float* out     = (float*)d_out;                 // [4*2048*512]
    float* idx_out = out + (size_t)NTOK * DIM;      // [8192] as float
    float* aux_out = idx_out + NTOK;                // [1]
    float* ws      = (float*)d_ws;

    hipLaunchKernelGGL(k_zero, dim3((NCODES + 16 + 255) / 256), dim3(256), 0, stream, ws);
    hipLaunchKernelGGL(k_h, dim3((NTOK * CD) / 256), dim3(256), 0, stream,
                       x, W_in, b_in, ws);
    hipLaunchKernelGGL(k_project, dim3(NTOK / 4), dim3(256), 0, stream,
                       ws, W_out, b_out, out, idx_out);
    hipLaunchKernelGGL(k_sparse, dim3(NTOK / 64), dim3(64), 0, stream,
                       ws + WS_H, ws);
    hipLaunchKernelGGL(k_final, dim3(1), dim3(256), 0, stream, ws, aux_out);
}

// Round 5
// 102.234 us; speedup vs baseline: 2.3373x; 1.0666x over previous
//
#include <hip/hip_runtime.h>
#include <math.h>

#define DIM 512
#define CD 14
#define NCODES 16384
#define NTOK 8192
#define EPS 1e-5f
#define LOG_EPS -11.5129254650f  // log(1e-5)
#define PTHRESH 1e-12f           // below this, p is invisible to f32 accumulation

// ws float layout:
//   [0 .. 16383]          avg_prob accumulators (atomic; zeroed by k_h tail blocks)
//   [16384 .. 18431]      per-block entropy partials (k_ps, plain writes)
//   [18432 .. 20479]      per-block commit partials  (k_ps, plain writes)
//   [20480 .. +NTOK*CD)   h[t][c] — numpy-f32-emulated projection
#define WS_ENT 16384
#define WS_COM (16384 + 2048)
#define WS_H   (16384 + 4096)
#define NBLK_H 1792   // NTOK*CD*4 threads / 256
#define NBLK_Z 64     // 64*256 == NCODES zero slots
#define NBLK_PS (NTOK / 4)

// Bit-exact emulation of numpy f32 einsum('bnd,cd->bnc'):
// sum_of_products_contig_contig_outstride0_two, BASELINE SIMD (SSE2/SSE3):
// 4 npyv lanes (no FMA: separate mul+add), 16-elem blocks, sub-block order
// 3,2,1,0, reduce = (l0+l1)+(l2+l3) via hadd, then one f32 add of b_in[c].
// VALIDATED round 3. Here each SSE lane chain runs on its own thread
// (4 threads/dot); lanes combined with shfl_xor in the exact hadd pairing
// (f32 add is commutative -> bit-identical).
__global__ __launch_bounds__(256) void k_h(
    const float* __restrict__ x, const float* __restrict__ W_in,
    const float* __restrict__ b_in, float* __restrict__ ws)
{
#pragma clang fp contract(off)
    const int tid = threadIdx.x;
    if (blockIdx.x >= NBLK_H) {  // tail blocks: zero avg_prob accumulators
        ws[(blockIdx.x - NBLK_H) * 256 + tid] = 0.f;
        return;
    }
    const int gid = blockIdx.x * 256 + tid;
    const int dot = gid >> 2;       // t*CD + c
    const int j   = gid & 3;        // SSE lane
    const int t = dot / CD;
    const int c = dot - t * CD;
    const float* xp = x + (size_t)t * DIM + j;
    const float* wp = W_in + (size_t)c * DIM + j;

    float a = 0.f;
    #pragma unroll 4
    for (int i = 0; i < 32; ++i) {
        const int base = i * 16;
        const float x3 = xp[base + 12], w3 = wp[base + 12];
        const float x2 = xp[base + 8],  w2 = wp[base + 8];
        const float x1 = xp[base + 4],  w1 = wp[base + 4];
        const float x0 = xp[base + 0],  w0 = wp[base + 0];
        a = (x3 * w3) + a;   // s=3 sub-block first (npy chain order)
        a = (x2 * w2) + a;
        a = (x1 * w1) + a;
        a = (x0 * w0) + a;
    }
    // hadd pairing: (a0+a1) + (a2+a3)
    const float s2  = a + __shfl_xor(a, 1);
    const float sum = s2 + __shfl_xor(s2, 2);
    if (j == 0) ws[WS_H + dot] = sum + b_in[c];
}

// Merged project_out + sparse clipped-softmax stats. One wave per token.
// p_j = (prod over mismatched bits of f_b)/Z, f_b = exp(-400|h_b|), Z = prod(1+f_b).
// Only subsets of hot bits (f >= PTHRESH) are visible to f32 accumulation.
// Identity: sum_j p_j*log(clip(p_j,eps)) = LOG_EPS + sum_enum p*(max(log p,LOG_EPS)-LOG_EPS)
__global__ __launch_bounds__(256) void k_ps(
    const float* __restrict__ hbuf, const float* __restrict__ W_out,
    const float* __restrict__ b_out, float* __restrict__ out,
    float* __restrict__ idx_out, float* __restrict__ ws)
{
    __shared__ float entred[4], comred[4];
    const int tid  = threadIdx.x;
    const int wave = tid >> 6, lane = tid & 63;
    const int tok  = blockIdx.x * 4 + wave;
    const float* hp = hbuf + (size_t)tok * CD;

    float s[CD];
    int jstar = 0;
    #pragma unroll
    for (int c = 0; c < CD; ++c) {
        const bool pos = hp[c] > 0.f;
        s[c] = pos ? 1.f : -1.f;
        jstar |= (pos ? 1 : 0) << (13 - c);
    }
    if (lane == 0) idx_out[tok] = (float)jstar;

    #pragma unroll
    for (int r = 0; r < 8; ++r) {
        const int d = r * 64 + lane;
        float v = b_out[d];
        const float* wo = W_out + (size_t)d * CD;
        #pragma unroll
        for (int c = 0; c < CD; ++c) v = fmaf(s[c], wo[c], v);
        out[(size_t)tok * DIM + d] = v;
    }

    if (lane == 0) {
        float f[CD];
        float commit = 0.f, Z = 1.f;
        #pragma unroll
        for (int c = 0; c < CD; ++c) {
            const float ah = fabsf(hp[c]);
            const float d = ah - 1.f;            // (h - sign(h))^2 == (|h|-1)^2
            commit = fmaf(d, d, commit);
            f[c] = __expf(-400.f * ah);
            Z *= 1.f + f[c];
        }
        const float invZ = 1.f / Z;

        int   hbit[CD];
        float hf[CD];
        int m = 0;
        #pragma unroll
        for (int c = 0; c < CD; ++c)
            if (f[c] >= PTHRESH) { hbit[m] = 1 << (13 - c); hf[m] = f[c]; ++m; }

        float ent = 0.f;
        const int nmask = 1 << m;
        for (int mask = 0; mask < nmask; ++mask) {
            float prod = 1.f;
            int flip = 0;
            for (int i = 0; i < m; ++i)
                if ((mask >> i) & 1) { prod *= hf[i]; flip |= hbit[i]; }
            const float p = prod * invZ;
            if (p < PTHRESH) continue;
            ent = fmaf(p, fmaxf(__logf(p), LOG_EPS) - LOG_EPS, ent);
            atomicAdd(&ws[jstar ^ flip], p);
        }
        entred[wave] = ent;
        comred[wave] = commit;
    }
    __syncthreads();
    if (tid == 0) {
        ws[WS_ENT + blockIdx.x] = (entred[0] + entred[1]) + (entred[2] + entred[3]);
        ws[WS_COM + blockIdx.x] = (comred[0] + comred[1]) + (comred[2] + comred[3]);
    }
}

__global__ __launch_bounds__(256) void k_final(
    const float* __restrict__ ws, float* __restrict__ aux_out)
{
    __shared__ float r1[256], r2[256], r3[256];
    const int tid = threadIdx.x;
    float acc = 0.f;
    for (int k = tid; k < NCODES; k += 256) {
        const float ap = ws[k] * (1.f / 8192.f);
        acc = fmaf(ap, __logf(fmaxf(ap, EPS)), acc);
    }
    float entp = 0.f, comp = 0.f;
    for (int k = tid; k < 2048; k += 256) {
        entp += ws[WS_ENT + k];
        comp += ws[WS_COM + k];
    }
    r1[tid] = acc; r2[tid] = entp; r3[tid] = comp;
    __syncthreads();
    for (int s = 128; s > 0; s >>= 1) {
        if (tid < s) {
            r1[tid] += r1[tid + s];
            r2[tid] += r2[tid + s];
            r3[tid] += r3[tid + s];
        }
        __syncthreads();
    }
    if (tid == 0) {
        const float cbH = -r1[0];
        // mean_t sum_j p log(clip p) == r2/NTOK + LOG_EPS
        const float psH = -(r2[0] * (1.f / 8192.f) + LOG_EPS);
        const float commit = r3[0] * (1.f / (8192.f * 14.f));
        aux_out[0] = (psH - cbH) * 0.1f + commit * 0.25f;
    }
}

extern "C" void kernel_launch(void* const* d_in, const int* in_sizes, int n_in,
                              void* d_out, int out_size, void* d_ws, size_t ws_size,
                              hipStream_t stream) {
    const float* x     = (const float*)d_in[0];
    const float* W_in  = (const float*)d_in[1];
    const float* b_in  = (const float*)d_in[2];
    const float* W_out = (const float*)d_in[3];
    const float* b_out = (const float*)d_in[4];
    // d_in[5] (codebook) is implicit in the factorized math.

    float* out     = (float*)d_out;                 // [4*2048*512]
    float* idx_out = out + (size_t)NTOK * DIM;      // [8192] as float
    float* aux_out = idx_out + NTOK;                // [1]
    float* ws      = (float*)d_ws;

    hipLaunchKernelGGL(k_h, dim3(NBLK_H + NBLK_Z), dim3(256), 0, stream,
                       x, W_in, b_in, ws);
    hipLaunchKernelGGL(k_ps, dim3(NBLK_PS), dim3(256), 0, stream,
                       ws + WS_H, W_out, b_out, out, idx_out, ws);
    hipLaunchKernelGGL(k_final, dim3(1), dim3(256), 0, stream, ws, aux_out);
}

// Round 6
// 54.177 us; speedup vs baseline: 4.4106x; 1.8870x over previous
//
#include <hip/hip_runtime.h>
#include <math.h>

#define DIM 512
#define CD 14
#define NCODES 16384
#define NTOK 8192
#define EPS 1e-5f
#define LOG_EPS -11.5129254650f  // log(1e-5)
#define PTHRESH 1e-12f           // below this, p is invisible to f32 accumulation

// ws float layout:
//   [0 .. 16383]          avg_prob accumulators (atomic; zeroed by k_h tail blocks)
//   [16384 .. 18431]      per-block entropy partials (k_ps, plain writes)
//   [18432 .. 20479]      per-block commit partials  (k_ps, plain writes)
//   [20480 .. +NTOK*16)   h[t][c] — numpy-f32-emulated projection, padded to 16/token
#define WS_ENT 16384
#define WS_COM (16384 + 2048)
#define WS_H   (16384 + 4096)
#define NBLK_H 1792   // NTOK*CD*4 threads / 256
#define NBLK_Z 64     // 64*256 == NCODES zero slots
#define NBLK_PS (NTOK / 4)
#define WT_S 513      // padded LDS row stride for transposed W_out

// Bit-exact emulation of numpy f32 einsum('bnd,cd->bnc'):
// sum_of_products_contig_contig_outstride0_two, BASELINE SIMD (SSE2/SSE3):
// 4 npyv lanes (no FMA: separate mul+add), 16-elem blocks, sub-block order
// 3,2,1,0, reduce = (l0+l1)+(l2+l3) via hadd, then one f32 add of b_in[c].
// VALIDATED round 3; lane-split validated round 4. DO NOT change arithmetic.
__global__ __launch_bounds__(256) void k_h(
    const float* __restrict__ x, const float* __restrict__ W_in,
    const float* __restrict__ b_in, float* __restrict__ ws)
{
#pragma clang fp contract(off)
    const int tid = threadIdx.x;
    if (blockIdx.x >= NBLK_H) {  // tail blocks: zero avg_prob accumulators
        ws[(blockIdx.x - NBLK_H) * 256 + tid] = 0.f;
        return;
    }
    const int gid = blockIdx.x * 256 + tid;
    const int dot = gid >> 2;       // t*CD + c
    const int j   = gid & 3;        // SSE lane
    const int t = dot / CD;
    const int c = dot - t * CD;
    const float* xp = x + (size_t)t * DIM + j;
    const float* wp = W_in + (size_t)c * DIM + j;

    float a = 0.f;
    #pragma unroll 4
    for (int i = 0; i < 32; ++i) {
        const int base = i * 16;
        const float x3 = xp[base + 12], w3 = wp[base + 12];
        const float x2 = xp[base + 8],  w2 = wp[base + 8];
        const float x1 = xp[base + 4],  w1 = wp[base + 4];
        const float x0 = xp[base + 0],  w0 = wp[base + 0];
        a = (x3 * w3) + a;   // s=3 sub-block first (npy chain order)
        a = (x2 * w2) + a;
        a = (x1 * w1) + a;
        a = (x0 * w0) + a;
    }
    // hadd pairing: (a0+a1) + (a2+a3)
    const float s2  = a + __shfl_xor(a, 1);
    const float sum = s2 + __shfl_xor(s2, 2);
    if (j == 0) ws[WS_H + (size_t)t * 16 + c] = sum + b_in[c];
}

// Merged project_out + sparse clipped-softmax stats. One wave per token.
// W_out staged transposed in LDS (conflict-free column reads); h/f staged in
// per-wave LDS (no runtime-indexed register arrays -> no scratch); subset
// enumeration parallel across 64 lanes.
__global__ __launch_bounds__(256) void k_ps(
    const float* __restrict__ hbuf, const float* __restrict__ W_out,
    const float* __restrict__ b_out, float* __restrict__ out,
    float* __restrict__ idx_out, float* __restrict__ ws)
{
    __shared__ float wT[CD * WT_S];
    __shared__ float h_lds[4][16];
    __shared__ float f_lds[4][16];
    __shared__ float entred[4], comred[4];

    const int tid  = threadIdx.x;
    const int wave = tid >> 6, lane = tid & 63;
    const int tok  = blockIdx.x * 4 + wave;

    // Stage W_out[512][14] -> wT[c][d] (transposed, padded). Coalesced float4 reads.
    #pragma unroll
    for (int i = 0; i < 7; ++i) {
        const int e = (i * 256 + tid) * 4;
        const float4 v = *(const float4*)(W_out + e);
        {const int idx = e + 0; const int d = idx / CD; wT[(idx - d * CD) * WT_S + d] = v.x;}
        {const int idx = e + 1; const int d = idx / CD; wT[(idx - d * CD) * WT_S + d] = v.y;}
        {const int idx = e + 2; const int d = idx / CD; wT[(idx - d * CD) * WT_S + d] = v.z;}
        {const int idx = e + 3; const int d = idx / CD; wT[(idx - d * CD) * WT_S + d] = v.w;}
    }
    if (lane < CD) {
        const float hv = hbuf[(size_t)tok * 16 + lane];
        h_lds[wave][lane] = hv;
        f_lds[wave][lane] = __expf(-400.f * fabsf(hv));
    }
    __syncthreads();

    // signs + jstar (wave-uniform; static unroll -> registers)
    float s[CD];
    int jstar = 0;
    #pragma unroll
    for (int c = 0; c < CD; ++c) {
        const bool pos = h_lds[wave][c] > 0.f;
        s[c] = pos ? 1.f : -1.f;
        jstar |= (pos ? 1 : 0) << (13 - c);
    }
    if (lane == 0) idx_out[tok] = (float)jstar;

    // out = s @ W_out^T + b_out; conflict-free LDS column reads
    #pragma unroll
    for (int r = 0; r < 8; ++r) {
        const int d = r * 64 + lane;
        float v = b_out[d];
        #pragma unroll
        for (int c = 0; c < CD; ++c) v = fmaf(s[c], wT[c * WT_S + d], v);
        out[(size_t)tok * DIM + d] = v;
    }

    // sparse clipped-softmax: p = (prod over flipped hot bits of f)/Z
    float Z = 1.f, commit = 0.f;
    int hot = 0;
    #pragma unroll
    for (int c = 0; c < CD; ++c) {
        const float fv = f_lds[wave][c];
        const float ah = fabsf(h_lds[wave][c]);
        const float dd = ah - 1.f;           // (h - sign(h))^2 == (|h|-1)^2
        commit = fmaf(dd, dd, commit);
        Z *= 1.f + fv;
        hot |= (fv >= PTHRESH ? 1 : 0) << c;
    }
    const float invZ = 1.f / Z;
    const int nmask = 1 << __popc(hot);

    float ent = 0.f;
    for (int base = 0; base < nmask; base += 64) {
        const int si = base + lane;           // subset index over hot bits
        float prod = 1.f;
        int flip = 0, pos = 0;
        #pragma unroll
        for (int c = 0; c < CD; ++c) {
            if ((hot >> c) & 1) {
                if ((si >> pos) & 1) {
                    prod *= f_lds[wave][c];
                    flip |= 1 << (13 - c);
                }
                ++pos;
            }
        }
        if (si < nmask) {
            const float p = prod * invZ;
            if (p >= PTHRESH) {
                ent = fmaf(p, fmaxf(__logf(p), LOG_EPS) - LOG_EPS, ent);
                atomicAdd(&ws[jstar ^ flip], p);
            }
        }
    }
    #pragma unroll
    for (int off = 32; off; off >>= 1) ent += __shfl_xor(ent, off);
    if (lane == 0) { entred[wave] = ent; comred[wave] = commit; }
    __syncthreads();
    if (tid == 0) {
        ws[WS_ENT + blockIdx.x] = (entred[0] + entred[1]) + (entred[2] + entred[3]);
        ws[WS_COM + blockIdx.x] = (comred[0] + comred[1]) + (comred[2] + comred[3]);
    }
}

__global__ __launch_bounds__(1024) void k_final(
    const float* __restrict__ ws, float* __restrict__ aux_out)
{
    __shared__ float r1[1024], r2[1024], r3[1024];
    const int tid = threadIdx.x;
    float acc = 0.f;
    #pragma unroll
    for (int k = 0; k < 16; ++k) {
        const float ap = ws[tid + k * 1024] * (1.f / 8192.f);
        acc = fmaf(ap, __logf(fmaxf(ap, EPS)), acc);
    }
    float entp = ws[WS_ENT + tid] + ws[WS_ENT + tid + 1024];
    float comp = ws[WS_COM + tid] + ws[WS_COM + tid + 1024];
    r1[tid] = acc; r2[tid] = entp; r3[tid] = comp;
    __syncthreads();
    for (int s = 512; s > 0; s >>= 1) {
        if (tid < s) {
            r1[tid] += r1[tid + s];
            r2[tid] += r2[tid + s];
            r3[tid] += r3[tid + s];
        }
        __syncthreads();
    }
    if (tid == 0) {
        const float cbH = -r1[0];
        // mean_t sum_j p log(clip p) == r2/NTOK + LOG_EPS
        const float psH = -(r2[0] * (1.f / 8192.f) + LOG_EPS);
        const float commit = r3[0] * (1.f / (8192.f * 14.f));
        aux_out[0] = (psH - cbH) * 0.1f + commit * 0.25f;
    }
}

extern "C" void kernel_launch(void* const* d_in, const int* in_sizes, int n_in,
                              void* d_out, int out_size, void* d_ws, size_t ws_size,
                              hipStream_t stream) {
    const float* x     = (const float*)d_in[0];
    const float* W_in  = (const float*)d_in[1];
    const float* b_in  = (const float*)d_in[2];
    const float* W_out = (const float*)d_in[3];
    const float* b_out = (const float*)d_in[4];
    // d_in[5] (codebook) is implicit in the factorized math.

    float* out     = (float*)d_out;                 // [4*2048*512]
    float* idx_out = out + (size_t)NTOK * DIM;      // [8192] as float
    float* aux_out = idx_out + NTOK;                // [1]
    float* ws      = (float*)d_ws;

    hipLaunchKernelGGL(k_h, dim3(NBLK_H + NBLK_Z), dim3(256), 0, stream,
                       x, W_in, b_in, ws);
    hipLaunchKernelGGL(k_ps, dim3(NBLK_PS), dim3(256), 0, stream,
                       ws + WS_H, W_out, b_out, out, idx_out, ws);
    hipLaunchKernelGGL(k_final, dim3(1), dim3(1024), 0, stream, ws, aux_out);
}